// Round 3
// baseline (191.401 us; speedup 1.0000x reference)
//
#include <hip/hip_runtime.h>

typedef unsigned long long u64;

#define G 512
#define T 128
#define P 256
#define B 512

// ---------------- workspace layout ----------------
// pv_ws  : B*4 u64        =  16 KB  (packed param_vals, linear bit order)
// psi_ws : G*T*4 u64      =   2 MB  (packed psi rows,  word j = floats [64j,64j+64))
// phi_ws : G*T*4 u64      =   2 MB  (packed phi rows)
// codes  : G*T u32        = 256 KB  (bit0 = psi_const, bit1 = phi_const)
#define PV_OFF    0
#define PSI_OFF   16384
#define PHI_OFF   (PSI_OFF + (size_t)G * T * 4 * 8)
#define CODES_OFF (PHI_OFF + (size_t)G * T * 4 * 8)
#define WS_NEEDED (CODES_OFF + (size_t)G * T * 4)

// Linear bit order everywhere: bit k of a row <-> float k of that row.
// Identical permutation on matrices and param_vals -> AND-parity preserved.

#define PSI_W (G * T * P / 64)     // 262144 output words
#define PHI_W PSI_W
#define PV_W  (B * P / 64)         // 2048
#define TOTW  (PSI_W + PHI_W + PV_W)     // 526336
#define PACK2_BLOCKS (TOTW / 256)        // 2056, exact

// ---------------- pack pass (copy-shaped: no ballot, no divergence) ----------
// One thread = one u64 word = 64 consecutive floats. 16 uint4 loads issued
// before any compute (sched_barrier pins them) -> deep MLP per wave; bits via
// branchless (u | -u) >> 31; one coalesced 8B store per lane.
__device__ __forceinline__ unsigned nzbit(unsigned u) {
    return (u | (0u - u)) >> 31;   // 1 iff u != 0
}

__global__ __launch_bounds__(256) void pack_words_kernel(
    const int*   __restrict__ psi_const,
    const int*   __restrict__ phi_const,
    const float* __restrict__ psi_params,
    const float* __restrict__ phi_params,
    const float* __restrict__ pv,
    u64*         __restrict__ psi_ws,
    u64*         __restrict__ phi_ws,
    u64*         __restrict__ pv_ws,
    unsigned*    __restrict__ codes_ws)
{
    const int tid = blockIdx.x * 256 + threadIdx.x;

    // const-bit codes: blocks 0..255 cover all G*T entries, coalesced
    if (tid < G * T) {
        unsigned pc = ((unsigned)psi_const[tid]) & 1u;
        unsigned qc = ((unsigned)phi_const[tid]) & 1u;
        codes_ws[tid] = pc | (qc << 1);
    }

    const float* s;
    u64*         d;
    if (tid < PSI_W) {
        s = psi_params + (size_t)tid * 64;
        d = psi_ws + tid;
    } else if (tid < PSI_W + PHI_W) {
        int w = tid - PSI_W;
        s = phi_params + (size_t)w * 64;
        d = phi_ws + w;
    } else {
        int w = tid - PSI_W - PHI_W;
        s = pv + (size_t)w * 64;
        d = pv_ws + w;
    }

    const uint4* sv = (const uint4*)s;
    uint4 f[16];
    #pragma unroll
    for (int i = 0; i < 16; ++i) f[i] = sv[i];
    __builtin_amdgcn_sched_barrier(0);   // keep all 16 loads in flight

    unsigned lo = 0, hi = 0;
    #pragma unroll
    for (int i = 0; i < 8; ++i) {
        lo |= nzbit(f[i].x) << (4 * i + 0);
        lo |= nzbit(f[i].y) << (4 * i + 1);
        lo |= nzbit(f[i].z) << (4 * i + 2);
        lo |= nzbit(f[i].w) << (4 * i + 3);
    }
    #pragma unroll
    for (int i = 8; i < 16; ++i) {
        hi |= nzbit(f[i].x) << (4 * (i - 8) + 0);
        hi |= nzbit(f[i].y) << (4 * (i - 8) + 1);
        hi |= nzbit(f[i].z) << (4 * (i - 8) + 2);
        hi |= nzbit(f[i].w) << (4 * (i - 8) + 3);
    }
    *d = ((u64)hi << 32) | (u64)lo;
}

// ---------------- compute pass (transposed, register-resident) ----------------
// Block = graph g, 512 threads (8 waves). Lane l owns terms t=l and t=l+64
// (psi+phi packed rows, 16 u64 = 32 VGPRs, coalesced load once per block).
// Loop over b: pv mask (32 B) via SGPR-uniform base; 32 consecutive b packed
// into one u32 per lane; 6-step XOR shuffle-reduce covers 32 outputs.
__global__ __launch_bounds__(512) void pi_trans_kernel(
    const u64*      __restrict__ psi_ws,
    const u64*      __restrict__ phi_ws,
    const unsigned* __restrict__ codes,
    const u64*      __restrict__ pv,
    float4*         __restrict__ out)
{
    const int g    = blockIdx.x;
    const int lane = threadIdx.x & 63;
    const int wv   = threadIdx.x >> 6;

    u64 ra[8], rb[8];   // ra: psi[0..3], phi[4..7] for t=lane; rb: same for t=lane+64
    {
        const ulonglong2* pA0 = (const ulonglong2*)(psi_ws + ((size_t)g * T + lane) * 4);
        const ulonglong2* pB0 = (const ulonglong2*)(phi_ws + ((size_t)g * T + lane) * 4);
        const ulonglong2* pA1 = (const ulonglong2*)(psi_ws + ((size_t)g * T + lane + 64) * 4);
        const ulonglong2* pB1 = (const ulonglong2*)(phi_ws + ((size_t)g * T + lane + 64) * 4);
        ulonglong2 x;
        x = pA0[0]; ra[0] = x.x; ra[1] = x.y;
        x = pA0[1]; ra[2] = x.x; ra[3] = x.y;
        x = pB0[0]; ra[4] = x.x; ra[5] = x.y;
        x = pB0[1]; ra[6] = x.x; ra[7] = x.y;
        x = pA1[0]; rb[0] = x.x; rb[1] = x.y;
        x = pA1[1]; rb[2] = x.x; rb[3] = x.y;
        x = pB1[0]; rb[4] = x.x; rb[5] = x.y;
        x = pB1[1]; rb[6] = x.x; rb[7] = x.y;
    }
    unsigned ca = codes[g * T + lane];
    unsigned cb = codes[g * T + lane + 64];
    unsigned pa = ca & 1u, qa = (ca >> 1) & 1u;
    unsigned pb = cb & 1u, qb = (cb >> 1) & 1u;

    #pragma unroll
    for (int grp = 0; grp < 2; ++grp) {
        int b0  = wv * 64 + grp * 32;
        int b0u = __builtin_amdgcn_readfirstlane(b0);   // SGPR base -> s_load
        const u64* vp = pv + (size_t)b0u * 4;

        unsigned acc = 0;
        #pragma unroll
        for (int i = 0; i < 32; ++i) {
            u64 v0 = vp[i * 4 + 0], v1 = vp[i * 4 + 1];
            u64 v2 = vp[i * 4 + 2], v3 = vp[i * 4 + 3];
            u64 m0 = (ra[0] & v0) ^ (ra[1] & v1) ^ (ra[2] & v2) ^ (ra[3] & v3);
            u64 m1 = (ra[4] & v0) ^ (ra[5] & v1) ^ (ra[6] & v2) ^ (ra[7] & v3);
            u64 m2 = (rb[0] & v0) ^ (rb[1] & v1) ^ (rb[2] & v2) ^ (rb[3] & v3);
            u64 m3 = (rb[4] & v0) ^ (rb[5] & v1) ^ (rb[6] & v2) ^ (rb[7] & v3);
            unsigned f0 = (unsigned)m0 ^ (unsigned)(m0 >> 32);
            unsigned f1 = (unsigned)m1 ^ (unsigned)(m1 >> 32);
            unsigned f2 = (unsigned)m2 ^ (unsigned)(m2 >> 32);
            unsigned f3 = (unsigned)m3 ^ (unsigned)(m3 >> 32);
            unsigned t01 = ((unsigned)__popc(f0) ^ pa) & ((unsigned)__popc(f1) ^ qa);
            unsigned t23 = ((unsigned)__popc(f2) ^ pb) & ((unsigned)__popc(f3) ^ qb);
            acc ^= ((t01 ^ t23) & 1u) << i;
        }

        unsigned red = acc;
        #pragma unroll
        for (int m = 1; m < 64; m <<= 1)
            red ^= __shfl_xor(red, m, 64);

        if (lane < 32) {
            int b = b0u + lane;
            float s = 1.0f - 2.0f * (float)((red >> lane) & 1u);
            out[(size_t)b * G + g] = make_float4(s, 0.0f, 0.0f, 0.0f);
        }
    }
}

// ---------------- fallback path (previous verified kernels) ----------------
struct __align__(16) U64x2 { u64 x, y; };

__global__ __launch_bounds__(256) void pack_pv_kernel(
    const float* __restrict__ pv, u64* __restrict__ out)
{
    int lane = threadIdx.x & 63;
    int wave = threadIdx.x >> 6;
    int row  = blockIdx.x * 4 + wave;
    const float4* src = (const float4*)(pv + (size_t)row * P);
    float4 f = src[lane];
    u64 w0 = __ballot(f.x != 0.0f);
    u64 w1 = __ballot(f.y != 0.0f);
    u64 w2 = __ballot(f.z != 0.0f);
    u64 w3 = __ballot(f.w != 0.0f);
    if (lane == 0) {
        out[row * 4 + 0] = w0;
        out[row * 4 + 1] = w1;
        out[row * 4 + 2] = w2;
        out[row * 4 + 3] = w3;
    }
}

__global__ __launch_bounds__(512) void pi_main_kernel(
    const int*   __restrict__ psi_const,
    const float* __restrict__ psi_params,
    const int*   __restrict__ phi_const,
    const float* __restrict__ phi_params,
    const u64*   __restrict__ pv,
    float4*      __restrict__ out)
{
    __shared__ __align__(16) u64 rows[T * 8];
    __shared__ unsigned code_sm[T];

    const int g    = blockIdx.x;
    const int tid  = threadIdx.x;
    const int lane = tid & 63;
    const int wave = tid >> 6;

    if (tid < T) {
        unsigned pc = ((unsigned)psi_const[g * T + tid]) & 1u;
        unsigned qc = ((unsigned)phi_const[g * T + tid]) & 1u;
        code_sm[tid] = pc | (qc << 1);
    }

    for (int i = 0; i < 32; ++i) {
        int r = wave * 32 + i;
        int t = r & (T - 1);
        const float* mat = (r < T) ? psi_params : phi_params;
        int off = (r < T) ? 0 : 4;
        const float4* src = (const float4*)(mat + ((size_t)g * T + t) * P);
        float4 f = src[lane];
        u64 w0 = __ballot(f.x != 0.0f);
        u64 w1 = __ballot(f.y != 0.0f);
        u64 w2 = __ballot(f.z != 0.0f);
        u64 w3 = __ballot(f.w != 0.0f);
        if (lane == 0) {
            U64x2* d = (U64x2*)&rows[t * 8 + off];
            U64x2 a; a.x = w0; a.y = w1;
            U64x2 c; c.x = w2; c.y = w3;
            d[0] = a;
            d[1] = c;
        }
    }
    __syncthreads();

    const int b = tid;
    const u64* v = pv + (size_t)b * 4;
    u64 v0 = v[0], v1 = v[1], v2 = v[2], v3 = v[3];

    unsigned e = 0;
    #pragma unroll 8
    for (int t = 0; t < T; ++t) {
        const U64x2* row = (const U64x2*)&rows[t * 8];
        U64x2 p0 = row[0], p1 = row[1], q0 = row[2], q1 = row[3];
        u64 ma = (p0.x & v0) ^ (p0.y & v1) ^ (p1.x & v2) ^ (p1.y & v3);
        u64 mb = (q0.x & v0) ^ (q0.y & v1) ^ (q1.x & v2) ^ (q1.y & v3);
        unsigned c = code_sm[t];
        e ^= (((unsigned)__popcll(ma) ^ c) & ((unsigned)__popcll(mb) ^ (c >> 1)));
    }
    e &= 1u;

    float s = 1.0f - 2.0f * (float)e;
    out[(size_t)b * G + g] = make_float4(s, 0.0f, 0.0f, 0.0f);
}

// ---------------- launch ----------------
extern "C" void kernel_launch(void* const* d_in, const int* in_sizes, int n_in,
                              void* d_out, int out_size, void* d_ws, size_t ws_size,
                              hipStream_t stream) {
    const int*   psi_const  = (const int*)  d_in[0];
    const float* psi_params = (const float*)d_in[1];
    const int*   phi_const  = (const int*)  d_in[2];
    const float* phi_params = (const float*)d_in[3];
    const float* param_vals = (const float*)d_in[4];

    if (ws_size >= WS_NEEDED) {
        u64*      pv_ws    = (u64*)((char*)d_ws + PV_OFF);
        u64*      psi_ws   = (u64*)((char*)d_ws + PSI_OFF);
        u64*      phi_ws   = (u64*)((char*)d_ws + PHI_OFF);
        unsigned* codes_ws = (unsigned*)((char*)d_ws + CODES_OFF);

        pack_words_kernel<<<PACK2_BLOCKS, 256, 0, stream>>>(
            psi_const, phi_const, psi_params, phi_params, param_vals,
            psi_ws, phi_ws, pv_ws, codes_ws);
        pi_trans_kernel<<<G, 512, 0, stream>>>(
            psi_ws, phi_ws, codes_ws, pv_ws, (float4*)d_out);
    } else {
        // previous verified path (16 KB workspace)
        u64* pv_packed = (u64*)d_ws;
        pack_pv_kernel<<<B / 4, 256, 0, stream>>>(param_vals, pv_packed);
        pi_main_kernel<<<G, 512, 0, stream>>>(psi_const, psi_params,
                                              phi_const, phi_params,
                                              pv_packed, (float4*)d_out);
    }
}

// Round 4
// 186.571 us; speedup vs baseline: 1.0259x; 1.0259x over previous
//
#include <hip/hip_runtime.h>

typedef unsigned long long u64;

#define G 512
#define T 128
#define P 256
#define B 512

// ---------------- workspace layout ----------------
// pv_ws : B*4 u64 = 16 KB  (packed param_vals, linear bit order)
#define WS_NEEDED 16384

// Linear bit order: bit k of word j of a row <-> float (j*64 + k) of that row.
// Identical permutation on matrices and param_vals -> AND-parity preserved.

__device__ __forceinline__ unsigned nzbit(unsigned u) {
    return (u | (0u - u)) >> 31;   // 1 iff u != 0 (fp32 0.0 has all-zero bits)
}

__device__ __forceinline__ u64 pack64(const uint4* sv) {
    uint4 f[16];
    #pragma unroll
    for (int i = 0; i < 16; ++i) f[i] = sv[i];
    __builtin_amdgcn_sched_barrier(0);   // keep all 16 loads in flight
    unsigned lo = 0, hi = 0;
    #pragma unroll
    for (int i = 0; i < 8; ++i) {
        lo |= nzbit(f[i].x) << (4 * i + 0);
        lo |= nzbit(f[i].y) << (4 * i + 1);
        lo |= nzbit(f[i].z) << (4 * i + 2);
        lo |= nzbit(f[i].w) << (4 * i + 3);
    }
    #pragma unroll
    for (int i = 8; i < 16; ++i) {
        hi |= nzbit(f[i].x) << (4 * (i - 8) + 0);
        hi |= nzbit(f[i].y) << (4 * (i - 8) + 1);
        hi |= nzbit(f[i].z) << (4 * (i - 8) + 2);
        hi |= nzbit(f[i].w) << (4 * (i - 8) + 3);
    }
    return ((u64)hi << 32) | (u64)lo;
}

// ---------------- tiny pv pack (0.5 MB, linear bit order) ----------------
__global__ __launch_bounds__(256) void pack_pv_linear_kernel(
    const float* __restrict__ pv, u64* __restrict__ out)
{
    int tid = blockIdx.x * 256 + threadIdx.x;          // 0..2047
    out[tid] = pack64((const uint4*)(pv + (size_t)tid * 64));
}

// ---------------- fused pack + compute ----------------
// Block = graph g (512 blocks x 512 threads, 2 blocks/CU at <=128 VGPR).
// Phase A: block packs its 2*128 rows (256 KB fp32) into LDS: 1024 u64 words,
//          2 words/thread, each word from 64 consecutive floats (16 uint4
//          loads batched -> deep MLP). fp32 is read exactly once, here.
// Phase B: verified pi_trans structure: lane l owns terms t=l, t=l+64 in
//          32 VGPRs; loop over b with SGPR-uniform pv masks; 32 b-results
//          bit-packed per lane; 6-step XOR shuffle-reduce; coalesced epilogue.
#define LSTR 9   // LDS row stride in u64 (pad 8->9 kills phase-B bank conflicts)

__global__ __launch_bounds__(512, 4) void pi_fused_kernel(
    const int*   __restrict__ psi_const,
    const int*   __restrict__ phi_const,
    const float* __restrict__ psi_params,
    const float* __restrict__ phi_params,
    const u64*   __restrict__ pv,
    float4*      __restrict__ out)
{
    __shared__ u64 lds[T * LSTR];    // [t][slot]: slot 0-3 psi words, 4-7 phi

    const int g    = blockIdx.x;
    const int tid  = threadIdx.x;
    const int lane = tid & 63;
    const int wv   = tid >> 6;

    const size_t rowbase = (size_t)g * T * P;

    // ---- Phase A ----
    #pragma unroll
    for (int rep = 0; rep < 2; ++rep) {
        int w    = rep * 512 + tid;      // 0..1023
        int t    = w >> 3;
        int slot = w & 7;
        int mat  = slot >> 2;
        int j    = slot & 3;
        const float* s = (mat ? phi_params : psi_params)
                         + rowbase + (size_t)t * P + j * 64;
        lds[t * LSTR + slot] = pack64((const uint4*)s);
    }
    __syncthreads();

    // ---- fragment load: terms t=lane and t=lane+64 ----
    u64 ra[8], rb[8];   // [0..3]=psi words, [4..7]=phi words
    #pragma unroll
    for (int k = 0; k < 8; ++k) ra[k] = lds[lane * LSTR + k];
    #pragma unroll
    for (int k = 0; k < 8; ++k) rb[k] = lds[(lane + 64) * LSTR + k];

    unsigned pa = ((unsigned)psi_const[g * T + lane]) & 1u;
    unsigned qa = ((unsigned)phi_const[g * T + lane]) & 1u;
    unsigned pb = ((unsigned)psi_const[g * T + lane + 64]) & 1u;
    unsigned qb = ((unsigned)phi_const[g * T + lane + 64]) & 1u;

    // ---- Phase B ----
    #pragma unroll
    for (int grp = 0; grp < 2; ++grp) {
        int b0  = wv * 64 + grp * 32;
        int b0u = __builtin_amdgcn_readfirstlane(b0);   // SGPR base -> s_load
        const u64* vp = pv + (size_t)b0u * 4;

        unsigned acc = 0;
        #pragma unroll
        for (int i = 0; i < 32; ++i) {
            u64 v0 = vp[i * 4 + 0], v1 = vp[i * 4 + 1];
            u64 v2 = vp[i * 4 + 2], v3 = vp[i * 4 + 3];
            u64 m0 = (ra[0] & v0) ^ (ra[1] & v1) ^ (ra[2] & v2) ^ (ra[3] & v3);
            u64 m1 = (ra[4] & v0) ^ (ra[5] & v1) ^ (ra[6] & v2) ^ (ra[7] & v3);
            u64 m2 = (rb[0] & v0) ^ (rb[1] & v1) ^ (rb[2] & v2) ^ (rb[3] & v3);
            u64 m3 = (rb[4] & v0) ^ (rb[5] & v1) ^ (rb[6] & v2) ^ (rb[7] & v3);
            unsigned f0 = (unsigned)m0 ^ (unsigned)(m0 >> 32);
            unsigned f1 = (unsigned)m1 ^ (unsigned)(m1 >> 32);
            unsigned f2 = (unsigned)m2 ^ (unsigned)(m2 >> 32);
            unsigned f3 = (unsigned)m3 ^ (unsigned)(m3 >> 32);
            unsigned t01 = ((unsigned)__popc(f0) ^ pa) & ((unsigned)__popc(f1) ^ qa);
            unsigned t23 = ((unsigned)__popc(f2) ^ pb) & ((unsigned)__popc(f3) ^ qb);
            acc ^= ((t01 ^ t23) & 1u) << i;
        }

        unsigned red = acc;
        #pragma unroll
        for (int m = 1; m < 64; m <<= 1)
            red ^= __shfl_xor(red, m, 64);

        if (lane < 32) {
            int b = b0u + lane;
            float s = 1.0f - 2.0f * (float)((red >> lane) & 1u);
            out[(size_t)b * G + g] = make_float4(s, 0.0f, 0.0f, 0.0f);
        }
    }
}

// ---------------- fallback path (round-0 verified kernels) ----------------
struct __align__(16) U64x2 { u64 x, y; };

__global__ __launch_bounds__(256) void pack_pv_kernel(
    const float* __restrict__ pv, u64* __restrict__ out)
{
    int lane = threadIdx.x & 63;
    int wave = threadIdx.x >> 6;
    int row  = blockIdx.x * 4 + wave;
    const float4* src = (const float4*)(pv + (size_t)row * P);
    float4 f = src[lane];
    u64 w0 = __ballot(f.x != 0.0f);
    u64 w1 = __ballot(f.y != 0.0f);
    u64 w2 = __ballot(f.z != 0.0f);
    u64 w3 = __ballot(f.w != 0.0f);
    if (lane == 0) {
        out[row * 4 + 0] = w0;
        out[row * 4 + 1] = w1;
        out[row * 4 + 2] = w2;
        out[row * 4 + 3] = w3;
    }
}

__global__ __launch_bounds__(512) void pi_main_kernel(
    const int*   __restrict__ psi_const,
    const float* __restrict__ psi_params,
    const int*   __restrict__ phi_const,
    const float* __restrict__ phi_params,
    const u64*   __restrict__ pv,
    float4*      __restrict__ out)
{
    __shared__ __align__(16) u64 rows[T * 8];
    __shared__ unsigned code_sm[T];

    const int g    = blockIdx.x;
    const int tid  = threadIdx.x;
    const int lane = tid & 63;
    const int wave = tid >> 6;

    if (tid < T) {
        unsigned pc = ((unsigned)psi_const[g * T + tid]) & 1u;
        unsigned qc = ((unsigned)phi_const[g * T + tid]) & 1u;
        code_sm[tid] = pc | (qc << 1);
    }

    for (int i = 0; i < 32; ++i) {
        int r = wave * 32 + i;
        int t = r & (T - 1);
        const float* mat = (r < T) ? psi_params : phi_params;
        int off = (r < T) ? 0 : 4;
        const float4* src = (const float4*)(mat + ((size_t)g * T + t) * P);
        float4 f = src[lane];
        u64 w0 = __ballot(f.x != 0.0f);
        u64 w1 = __ballot(f.y != 0.0f);
        u64 w2 = __ballot(f.z != 0.0f);
        u64 w3 = __ballot(f.w != 0.0f);
        if (lane == 0) {
            U64x2* d = (U64x2*)&rows[t * 8 + off];
            U64x2 a; a.x = w0; a.y = w1;
            U64x2 c; c.x = w2; c.y = w3;
            d[0] = a;
            d[1] = c;
        }
    }
    __syncthreads();

    const int b = tid;
    const u64* v = pv + (size_t)b * 4;
    u64 v0 = v[0], v1 = v[1], v2 = v[2], v3 = v[3];

    unsigned e = 0;
    #pragma unroll 8
    for (int t = 0; t < T; ++t) {
        const U64x2* row = (const U64x2*)&rows[t * 8];
        U64x2 p0 = row[0], p1 = row[1], q0 = row[2], q1 = row[3];
        u64 ma = (p0.x & v0) ^ (p0.y & v1) ^ (p1.x & v2) ^ (p1.y & v3);
        u64 mb = (q0.x & v0) ^ (q0.y & v1) ^ (q1.x & v2) ^ (q1.y & v3);
        unsigned c = code_sm[t];
        e ^= (((unsigned)__popcll(ma) ^ c) & ((unsigned)__popcll(mb) ^ (c >> 1)));
    }
    e &= 1u;

    float s = 1.0f - 2.0f * (float)e;
    out[(size_t)b * G + g] = make_float4(s, 0.0f, 0.0f, 0.0f);
}

// ---------------- launch ----------------
extern "C" void kernel_launch(void* const* d_in, const int* in_sizes, int n_in,
                              void* d_out, int out_size, void* d_ws, size_t ws_size,
                              hipStream_t stream) {
    const int*   psi_const  = (const int*)  d_in[0];
    const float* psi_params = (const float*)d_in[1];
    const int*   phi_const  = (const int*)  d_in[2];
    const float* phi_params = (const float*)d_in[3];
    const float* param_vals = (const float*)d_in[4];

    u64* pv_ws = (u64*)d_ws;   // 16 KB

    if (ws_size >= WS_NEEDED) {
        pack_pv_linear_kernel<<<(B * P / 64) / 256, 256, 0, stream>>>(
            param_vals, pv_ws);
        pi_fused_kernel<<<G, 512, 0, stream>>>(
            psi_const, phi_const, psi_params, phi_params,
            pv_ws, (float4*)d_out);
    } else {
        pack_pv_kernel<<<B / 4, 256, 0, stream>>>(param_vals, pv_ws);
        pi_main_kernel<<<G, 512, 0, stream>>>(psi_const, psi_params,
                                              phi_const, phi_params,
                                              pv_ws, (float4*)d_out);
    }
}

// Round 5
// 185.111 us; speedup vs baseline: 1.0340x; 1.0079x over previous
//
#include <hip/hip_runtime.h>

typedef unsigned long long u64;

#define G 512
#define T 128
#define P 256
#define B 512

// ---------------- workspace layout ----------------
// pv_ws  : B*4 u64   = 16 KB  (packed param_vals, linear bit order)
// par_ws : G*16 u32  = 32 KB  (parity bits, [g][b/32], bit = b&31)
#define PV_OFF    0
#define PAR_OFF   16384
#define WS_NEEDED (PAR_OFF + (size_t)G * 16 * 4)

// Linear bit order: bit k of word j of a row <-> float (j*64 + k).
// Same permutation on matrices and param_vals -> AND-parity preserved.

__device__ __forceinline__ unsigned nzbit(unsigned u) {
    return (u | (0u - u)) >> 31;   // 1 iff u != 0
}

__device__ __forceinline__ u64 pack64(const uint4* sv) {
    uint4 f[16];
    #pragma unroll
    for (int i = 0; i < 16; ++i) f[i] = sv[i];
    __builtin_amdgcn_sched_barrier(0);   // keep the 16 loads batched
    unsigned lo = 0, hi = 0;
    #pragma unroll
    for (int i = 0; i < 8; ++i) {
        lo |= nzbit(f[i].x) << (4 * i + 0);
        lo |= nzbit(f[i].y) << (4 * i + 1);
        lo |= nzbit(f[i].z) << (4 * i + 2);
        lo |= nzbit(f[i].w) << (4 * i + 3);
    }
    #pragma unroll
    for (int i = 8; i < 16; ++i) {
        hi |= nzbit(f[i].x) << (4 * (i - 8) + 0);
        hi |= nzbit(f[i].y) << (4 * (i - 8) + 1);
        hi |= nzbit(f[i].z) << (4 * (i - 8) + 2);
        hi |= nzbit(f[i].w) << (4 * (i - 8) + 3);
    }
    return ((u64)hi << 32) | (u64)lo;
}

// ---------------- k1: pack pv + zero parity workspace ----------------
__global__ __launch_bounds__(256) void pack_pv_zero_kernel(
    const float* __restrict__ pv, u64* __restrict__ pv_ws,
    uint4* __restrict__ par_zero)
{
    int tid = blockIdx.x * 256 + threadIdx.x;            // 0..2047
    pv_ws[tid] = pack64((const uint4*)(pv + (size_t)tid * 64));
    par_zero[tid] = make_uint4(0, 0, 0, 0);              // 2048*16B = 32 KB
}

// ---------------- k2: half-graph pack + parity ----------------
// Block = (g, half): packs 64 terms x 2 matrices (128 KB fp32) into 4.5 KB
// LDS, then lane l owns term half*64+l; wave wv covers b in [wv*128, wv*128+128)
// with SGPR-uniform pv masks; 128 parity bits per lane packed into 4 u32,
// XOR shuffle-reduced across the wave, atomicXor'd into par_ws[g][..].
#define LSTR 9   // padded u64 stride per term

__global__ __launch_bounds__(256, 6) void pi_half_kernel(
    const int*   __restrict__ psi_const,
    const int*   __restrict__ phi_const,
    const float* __restrict__ psi_params,
    const float* __restrict__ phi_params,
    const u64*   __restrict__ pv,
    unsigned*    __restrict__ par_ws)
{
    __shared__ u64 lds[64 * LSTR];

    const int g    = blockIdx.x >> 1;
    const int half = blockIdx.x & 1;
    const int tid  = threadIdx.x;
    const int lane = tid & 63;
    const int wv   = tid >> 6;

    const size_t rowbase = ((size_t)g * T + half * 64) * P;

    // ---- Phase A: pack 512 u64 words, 2 per thread ----
    #pragma unroll
    for (int rep = 0; rep < 2; ++rep) {
        int w    = rep * 256 + tid;        // 0..511
        int t    = w >> 3;
        int slot = w & 7;                  // 0-3 psi, 4-7 phi
        const float* s = (slot < 4 ? psi_params : phi_params)
                         + rowbase + (size_t)t * P + (slot & 3) * 64;
        lds[t * LSTR + slot] = pack64((const uint4*)s);
    }
    __syncthreads();

    // ---- fragment: term t0 = half*64 + lane ----
    u64 ra[8];
    #pragma unroll
    for (int k = 0; k < 8; ++k) ra[k] = lds[lane * LSTR + k];

    const int tg = g * T + half * 64 + lane;
    unsigned pa = ((unsigned)psi_const[tg]) & 1u;
    unsigned qa = ((unsigned)phi_const[tg]) & 1u;

    // ---- Phase B: 4 groups of 32 b each ----
    unsigned a0, a1, a2, a3;
    #pragma unroll
    for (int q = 0; q < 4; ++q) {
        int b0  = wv * 128 + q * 32;
        int b0u = __builtin_amdgcn_readfirstlane(b0);    // SGPR base -> s_load
        const u64* vp = pv + (size_t)b0u * 4;

        unsigned acc = 0;
        #pragma unroll
        for (int i = 0; i < 32; ++i) {
            u64 v0 = vp[i * 4 + 0], v1 = vp[i * 4 + 1];
            u64 v2 = vp[i * 4 + 2], v3 = vp[i * 4 + 3];
            u64 m0 = (ra[0] & v0) ^ (ra[1] & v1) ^ (ra[2] & v2) ^ (ra[3] & v3);
            u64 m1 = (ra[4] & v0) ^ (ra[5] & v1) ^ (ra[6] & v2) ^ (ra[7] & v3);
            unsigned f0 = (unsigned)m0 ^ (unsigned)(m0 >> 32);
            unsigned f1 = (unsigned)m1 ^ (unsigned)(m1 >> 32);
            unsigned t01 = ((unsigned)__popc(f0) ^ pa) & ((unsigned)__popc(f1) ^ qa);
            acc ^= (t01 & 1u) << i;
        }
        if (q == 0) a0 = acc; else if (q == 1) a1 = acc;
        else if (q == 2) a2 = acc; else a3 = acc;
    }

    // ---- wave XOR-reduce all four words, then 4 atomics ----
    #pragma unroll
    for (int m = 1; m < 64; m <<= 1) {
        a0 ^= __shfl_xor(a0, m, 64);
        a1 ^= __shfl_xor(a1, m, 64);
        a2 ^= __shfl_xor(a2, m, 64);
        a3 ^= __shfl_xor(a3, m, 64);
    }
    if (lane < 4) {
        unsigned myv = (lane == 0) ? a0 : (lane == 1) ? a1 : (lane == 2) ? a2 : a3;
        atomicXor(&par_ws[g * 16 + wv * 4 + lane], myv);
    }
}

// ---------------- k3: epilogue, coalesced sign stores ----------------
__global__ __launch_bounds__(256) void epilogue_kernel(
    const unsigned* __restrict__ par_ws, float4* __restrict__ out)
{
    int id = blockIdx.x * 256 + threadIdx.x;     // 0..262143 = b*512 + g
    int b  = id >> 9;
    int gg = id & 511;
    unsigned w = par_ws[gg * 16 + (b >> 5)];
    float s = 1.0f - 2.0f * (float)((w >> (b & 31)) & 1u);
    out[id] = make_float4(s, 0.0f, 0.0f, 0.0f);
}

// ---------------- fallback path (round-0 verified kernels) ----------------
struct __align__(16) U64x2 { u64 x, y; };

__global__ __launch_bounds__(256) void pack_pv_kernel(
    const float* __restrict__ pv, u64* __restrict__ out)
{
    int lane = threadIdx.x & 63;
    int wave = threadIdx.x >> 6;
    int row  = blockIdx.x * 4 + wave;
    const float4* src = (const float4*)(pv + (size_t)row * P);
    float4 f = src[lane];
    u64 w0 = __ballot(f.x != 0.0f);
    u64 w1 = __ballot(f.y != 0.0f);
    u64 w2 = __ballot(f.z != 0.0f);
    u64 w3 = __ballot(f.w != 0.0f);
    if (lane == 0) {
        out[row * 4 + 0] = w0;
        out[row * 4 + 1] = w1;
        out[row * 4 + 2] = w2;
        out[row * 4 + 3] = w3;
    }
}

__global__ __launch_bounds__(512) void pi_main_kernel(
    const int*   __restrict__ psi_const,
    const float* __restrict__ psi_params,
    const int*   __restrict__ phi_const,
    const float* __restrict__ phi_params,
    const u64*   __restrict__ pv,
    float4*      __restrict__ out)
{
    __shared__ __align__(16) u64 rows[T * 8];
    __shared__ unsigned code_sm[T];

    const int g    = blockIdx.x;
    const int tid  = threadIdx.x;
    const int lane = tid & 63;
    const int wave = tid >> 6;

    if (tid < T) {
        unsigned pc = ((unsigned)psi_const[g * T + tid]) & 1u;
        unsigned qc = ((unsigned)phi_const[g * T + tid]) & 1u;
        code_sm[tid] = pc | (qc << 1);
    }

    for (int i = 0; i < 32; ++i) {
        int r = wave * 32 + i;
        int t = r & (T - 1);
        const float* mat = (r < T) ? psi_params : phi_params;
        int off = (r < T) ? 0 : 4;
        const float4* src = (const float4*)(mat + ((size_t)g * T + t) * P);
        float4 f = src[lane];
        u64 w0 = __ballot(f.x != 0.0f);
        u64 w1 = __ballot(f.y != 0.0f);
        u64 w2 = __ballot(f.z != 0.0f);
        u64 w3 = __ballot(f.w != 0.0f);
        if (lane == 0) {
            U64x2* d = (U64x2*)&rows[t * 8 + off];
            U64x2 a; a.x = w0; a.y = w1;
            U64x2 c; c.x = w2; c.y = w3;
            d[0] = a;
            d[1] = c;
        }
    }
    __syncthreads();

    const int b = tid;
    const u64* v = pv + (size_t)b * 4;
    u64 v0 = v[0], v1 = v[1], v2 = v[2], v3 = v[3];

    unsigned e = 0;
    #pragma unroll 8
    for (int t = 0; t < T; ++t) {
        const U64x2* row = (const U64x2*)&rows[t * 8];
        U64x2 p0 = row[0], p1 = row[1], q0 = row[2], q1 = row[3];
        u64 ma = (p0.x & v0) ^ (p0.y & v1) ^ (p1.x & v2) ^ (p1.y & v3);
        u64 mb = (q0.x & v0) ^ (q0.y & v1) ^ (q1.x & v2) ^ (q1.y & v3);
        unsigned c = code_sm[t];
        e ^= (((unsigned)__popcll(ma) ^ c) & ((unsigned)__popcll(mb) ^ (c >> 1)));
    }
    e &= 1u;

    float s = 1.0f - 2.0f * (float)e;
    out[(size_t)b * G + g] = make_float4(s, 0.0f, 0.0f, 0.0f);
}

// ---------------- launch ----------------
extern "C" void kernel_launch(void* const* d_in, const int* in_sizes, int n_in,
                              void* d_out, int out_size, void* d_ws, size_t ws_size,
                              hipStream_t stream) {
    const int*   psi_const  = (const int*)  d_in[0];
    const float* psi_params = (const float*)d_in[1];
    const int*   phi_const  = (const int*)  d_in[2];
    const float* phi_params = (const float*)d_in[3];
    const float* param_vals = (const float*)d_in[4];

    if (ws_size >= WS_NEEDED) {
        u64*      pv_ws  = (u64*)((char*)d_ws + PV_OFF);
        unsigned* par_ws = (unsigned*)((char*)d_ws + PAR_OFF);

        pack_pv_zero_kernel<<<8, 256, 0, stream>>>(
            param_vals, pv_ws, (uint4*)par_ws);
        pi_half_kernel<<<G * 2, 256, 0, stream>>>(
            psi_const, phi_const, psi_params, phi_params, pv_ws, par_ws);
        epilogue_kernel<<<(B * G) / 256, 256, 0, stream>>>(
            par_ws, (float4*)d_out);
    } else {
        u64* pv_packed = (u64*)d_ws;
        pack_pv_kernel<<<B / 4, 256, 0, stream>>>(param_vals, pv_packed);
        pi_main_kernel<<<G, 512, 0, stream>>>(psi_const, psi_params,
                                              phi_const, phi_params,
                                              pv_packed, (float4*)d_out);
    }
}